// Round 6
// baseline (258.065 us; speedup 1.0000x reference)
//
#include <hip/hip_runtime.h>

// Output: [16, 46, 526, 518] f32.  Input: [16, 32, 512, 512] f32.
// Per output row (n,c,h):  out_row = [ in[1]x3 , in_row[0..511] , in[510]x3 ]
// where in_row = x[n, cmap(c), hmap(h), :].
//
// R5 structure (ci-sorted plane order + bijective XCD chunk swizzle,
// 128 lanes/row, 4 floats/lane) with MLP=4: each thread serves 4 rows,
// issuing 4 independent dwordx4 loads before any store.

using f4 = __attribute__((ext_vector_type(4))) float;

// processing-order -> output channel c, sorted by ci=cmap(c):
// ci=0:{2,4,36,38} ci=1:{5,39..45} ci=2..29:{6..33} ci=30:{0,34} ci=31:{1,3,35,37}
__device__ const unsigned char cperm_tab[46] = {
    2, 4, 36, 38,
    5, 39, 40, 41, 42, 43, 44, 45,
    6, 7, 8, 9, 10, 11, 12, 13, 14, 15, 16, 17, 18, 19,
    20, 21, 22, 23, 24, 25, 26, 27, 28, 29, 30, 31, 32, 33,
    0, 34,
    1, 3, 35, 37
};

__device__ __forceinline__ int hmap(int d) {
    // reflect(+-2) -> edge(+-2) -> edge(+3 front) -> reflect(+3 front), H=512
    if (d <= 8)   return 2;
    if (d == 9)   return 1;
    if (d <= 521) return d - 10;
    return (d == 522) ? 510 : 509;
}

__device__ __forceinline__ void row_ptrs(const float* __restrict__ x,
                                         float* __restrict__ out,
                                         unsigned int lrow,
                                         const float** pin, float** pout) {
    const unsigned int p  = lrow / 526u;            // logical plane index
    const int          h  = (int)(lrow - p * 526u);
    const unsigned int n  = p / 46u;
    const unsigned int po = p - n * 46u;            // position in ci-sorted order
    const int c = cperm_tab[po];
    int ci;                                          // ci follows from sort order
    if      (po < 4)  ci = 0;
    else if (po < 12) ci = 1;
    else if (po < 40) ci = (int)po - 10;
    else if (po < 42) ci = 30;
    else              ci = 31;
    *pin  = x   + ((((size_t)n * 32 + ci) * 512 + hmap(h)) << 9);
    *pout = out + ((size_t)(n * 46u + (unsigned)c) * 526u + (unsigned)h) * 518u;
}

__global__ __launch_bounds__(256) void pad_rows_kernel(const float* __restrict__ x,
                                                       float* __restrict__ out) {
    // bijective XCD chunk swizzle: 48392 = 8 * 6049 blocks
    const unsigned int d = blockIdx.x;
    const unsigned int l = (d & 7u) * 6049u + (d >> 3);

    const int tt   = threadIdx.x & 127;             // lane within row
    const int half = threadIdx.x >> 7;              // 0/1
    const unsigned int base = l * 8u + (unsigned)half;   // 8 rows per block

    const float *in0, *in1, *in2, *in3;
    float *o0, *o1, *o2, *o3;
    row_ptrs(x, out, base,      &in0, &o0);
    row_ptrs(x, out, base + 2u, &in1, &o1);
    row_ptrs(x, out, base + 4u, &in2, &o2);
    row_ptrs(x, out, base + 6u, &in3, &o3);

    // four independent 16B loads in flight
    const f4 a = reinterpret_cast<const f4*>(in0)[tt];
    const f4 b = reinterpret_cast<const f4*>(in1)[tt];
    const f4 cc = reinterpret_cast<const f4*>(in2)[tt];
    const f4 dd = reinterpret_cast<const f4*>(in3)[tt];

    // lane-contiguous interior stores
    *reinterpret_cast<f4*>(o0 + 3 + 4 * tt) = a;
    *reinterpret_cast<f4*>(o1 + 3 + 4 * tt) = b;
    *reinterpret_cast<f4*>(o2 + 3 + 4 * tt) = cc;
    *reinterpret_cast<f4*>(o3 + 3 + 4 * tt) = dd;

    if (tt == 0) {
        // out[0..2] = in[1]  (.y of the first quad)
        o0[0] = a.y;  o0[1] = a.y;  o0[2] = a.y;
        o1[0] = b.y;  o1[1] = b.y;  o1[2] = b.y;
        o2[0] = cc.y; o2[1] = cc.y; o2[2] = cc.y;
        o3[0] = dd.y; o3[1] = dd.y; o3[2] = dd.y;
    } else if (tt == 127) {
        // out[515..517] = in[510]  (.z of the last quad)
        o0[515] = a.z;  o0[516] = a.z;  o0[517] = a.z;
        o1[515] = b.z;  o1[516] = b.z;  o1[517] = b.z;
        o2[515] = cc.z; o2[516] = cc.z; o2[517] = cc.z;
        o3[515] = dd.z; o3[516] = dd.z; o3[517] = dd.z;
    }
}

extern "C" void kernel_launch(void* const* d_in, const int* in_sizes, int n_in,
                              void* d_out, int out_size, void* d_ws, size_t ws_size,
                              hipStream_t stream) {
    const float* x = (const float*)d_in[0];
    float* out = (float*)d_out;
    // total output rows = 16*46*526 = 387,136 = 8 * 48,392
    pad_rows_kernel<<<48392, 256, 0, stream>>>(x, out);
}

// Round 7
// 248.082 us; speedup vs baseline: 1.0402x; 1.0402x over previous
//
#include <hip/hip_runtime.h>

// Output: [16, 46, 526, 518] f32.  Input: [16, 32, 512, 512] f32.
// Per output row (n,c,h):  out_row = [ in[1]x3 , in_row[0..511] , in[510]x3 ]
// where in_row = x[n, cmap(c), hmap(h), :].
//
// R5 (best: 248.9 us): 128 lanes/row, 4 floats/lane, 2 rows/thread (MLP=2),
// ci-sorted plane processing order + bijective XCD chunk swizzle.
// R3 (NT + gapped stores) and R6 (MLP=4) both regressed — reverted.

using f4 = __attribute__((ext_vector_type(4))) float;

// processing-order -> output channel c, sorted by ci=cmap(c):
// ci=0:{2,4,36,38} ci=1:{5,39..45} ci=2..29:{6..33} ci=30:{0,34} ci=31:{1,3,35,37}
__device__ const unsigned char cperm_tab[46] = {
    2, 4, 36, 38,
    5, 39, 40, 41, 42, 43, 44, 45,
    6, 7, 8, 9, 10, 11, 12, 13, 14, 15, 16, 17, 18, 19,
    20, 21, 22, 23, 24, 25, 26, 27, 28, 29, 30, 31, 32, 33,
    0, 34,
    1, 3, 35, 37
};

__device__ __forceinline__ int hmap(int d) {
    // reflect(+-2) -> edge(+-2) -> edge(+3 front) -> reflect(+3 front), H=512
    if (d <= 8)   return 2;
    if (d == 9)   return 1;
    if (d <= 521) return d - 10;
    return (d == 522) ? 510 : 509;
}

__device__ __forceinline__ void row_ptrs(const float* __restrict__ x,
                                         float* __restrict__ out,
                                         unsigned int lrow,
                                         const float** pin, float** pout) {
    const unsigned int p  = lrow / 526u;            // logical plane index
    const int          h  = (int)(lrow - p * 526u);
    const unsigned int n  = p / 46u;
    const unsigned int po = p - n * 46u;            // position in ci-sorted order
    const int c = cperm_tab[po];
    int ci;                                          // ci follows from sort order
    if      (po < 4)  ci = 0;
    else if (po < 12) ci = 1;
    else if (po < 40) ci = (int)po - 10;
    else if (po < 42) ci = 30;
    else              ci = 31;
    *pin  = x   + ((((size_t)n * 32 + ci) * 512 + hmap(h)) << 9);
    *pout = out + ((size_t)(n * 46u + (unsigned)c) * 526u + (unsigned)h) * 518u;
}

__global__ __launch_bounds__(256) void pad_rows_kernel(const float* __restrict__ x,
                                                       float* __restrict__ out) {
    // bijective XCD chunk swizzle: 96784 = 8 * 12098 blocks
    const unsigned int d = blockIdx.x;
    const unsigned int l = (d & 7u) * 12098u + (d >> 3);

    const int tt   = threadIdx.x & 127;             // lane within row
    const int half = threadIdx.x >> 7;              // 0/1
    const unsigned int base  = l * 4u;
    const unsigned int lrowA = base + half;
    const unsigned int lrowB = lrowA + 2u;

    const float *inA, *inB;
    float *outA, *outB;
    row_ptrs(x, out, lrowA, &inA, &outA);
    row_ptrs(x, out, lrowB, &inB, &outB);

    // two independent 16B loads in flight
    const f4 a = reinterpret_cast<const f4*>(inA)[tt];
    const f4 b = reinterpret_cast<const f4*>(inB)[tt];

    // lane-contiguous interior stores
    *reinterpret_cast<f4*>(outA + 3 + 4 * tt) = a;
    *reinterpret_cast<f4*>(outB + 3 + 4 * tt) = b;

    if (tt == 0) {
        const float ea = a.y, eb = b.y;             // in[1]
        outA[0] = ea; outA[1] = ea; outA[2] = ea;
        outB[0] = eb; outB[1] = eb; outB[2] = eb;
    } else if (tt == 127) {
        const float ea = a.z, eb = b.z;             // in[510]
        outA[515] = ea; outA[516] = ea; outA[517] = ea;
        outB[515] = eb; outB[516] = eb; outB[517] = eb;
    }
}

extern "C" void kernel_launch(void* const* d_in, const int* in_sizes, int n_in,
                              void* d_out, int out_size, void* d_ws, size_t ws_size,
                              hipStream_t stream) {
    const float* x = (const float*)d_in[0];
    float* out = (float*)d_out;
    // total output rows = 16*46*526 = 387,136 = 4 * 96,784
    pad_rows_kernel<<<96784, 256, 0, stream>>>(x, out);
}